// Round 1
// baseline (2360.539 us; speedup 1.0000x reference)
//
#include <hip/hip_runtime.h>
#include <math.h>

#define LL 24
#define DD 512
#define HH 16
#define HDD 32
#define FFD 2048
#define VV 1025
#define SS 2047
#define TKV 2048
#define TYY 1535

// d_out layout (floats), concatenated in reference return order
constexpr size_t O_YNEW  = 0;                                  // 1537
constexpr size_t O_KOUT  = 1537;                               // 24*2048*512
constexpr size_t O_VOUT  = O_KOUT + (size_t)LL*TKV*DD;
constexpr size_t O_YEMB  = O_VOUT + (size_t)LL*TKV*DD;         // 1536*512
constexpr size_t O_LOGITS= O_YEMB + (size_t)(TYY+1)*DD;        // 1025
constexpr size_t O_SAMP  = O_LOGITS + VV;                      // 1

// ws layout (floats)
constexpr int W_X0   = 0;      // 512
constexpr int W_XIN  = 512;    // 512
constexpr int W_QKV  = 1024;   // 1536
constexpr int W_PART = 2560;   // 16*16*34 = 8704
constexpr int W_RES  = 11264;  // 512
constexpr int W_XLN  = 11776;  // 512
constexpr int W_FF   = 12288;  // 512

__device__ __forceinline__ float dot4(float4 a, float4 b){
  return a.x*b.x + a.y*b.y + a.z*b.z + a.w*b.w;
}

__global__ __launch_bounds__(256) void setup_kernel(
    const int* __restrict__ y, const float* __restrict__ yemb,
    const float* __restrict__ emb, const float* __restrict__ alpha,
    float* __restrict__ out, float* __restrict__ wsf)
{
  int tid = blockIdx.x*256 + threadIdx.x;
  int nth = gridDim.x*256;
  for (int i = tid; i < TYY*DD; i += nth) out[O_YEMB + i] = yemb[i];
  if (tid < 1536) out[O_YNEW + tid] = (float)y[tid];
  if (tid < DD) {
    int tok = y[1535];
    float e = emb[(size_t)tok*DD + tid];
    out[O_YEMB + (size_t)TYY*DD + tid] = e;
    int i2 = tid >> 1;
    float ang = 1535.0f * expf((float)(2*i2) * (-9.210340371976184f/512.0f));
    float pe = (tid & 1) ? cosf(ang) : sinf(ang);
    wsf[W_X0 + tid] = e + alpha[0]*pe;
  }
}

// qkv projection; also finalizes previous layer's LN2 to form xin
__global__ __launch_bounds__(256) void qkv_kernel(int l,
    const float* __restrict__ ipw, const float* __restrict__ ipb,
    const float* __restrict__ l2w, const float* __restrict__ l2b,
    float* __restrict__ out, float* __restrict__ wsf)
{
  __shared__ __align__(16) float xin[DD];
  __shared__ float red[256];
  int t = threadIdx.x;
  if (l == 0) {
    xin[t] = wsf[W_X0+t]; xin[t+256] = wsf[W_X0+t+256];
    __syncthreads();
  } else {
    float r0 = wsf[W_XLN+t] + wsf[W_FF+t];
    float r1 = wsf[W_XLN+t+256] + wsf[W_FF+t+256];
    red[t] = r0+r1; __syncthreads();
    for (int off=128; off; off>>=1){ if (t<off) red[t]+=red[t+off]; __syncthreads(); }
    float mean = red[0] * (1.0f/512.0f); __syncthreads();
    float d0=r0-mean, d1=r1-mean;
    red[t]=d0*d0+d1*d1; __syncthreads();
    for (int off=128; off; off>>=1){ if (t<off) red[t]+=red[t+off]; __syncthreads(); }
    float rstd = rsqrtf(red[0]*(1.0f/512.0f) + 1e-5f); __syncthreads();
    const float* g = l2w + (size_t)(l-1)*DD;
    const float* b = l2b + (size_t)(l-1)*DD;
    xin[t]     = d0*rstd*g[t]    + b[t];
    xin[t+256] = d1*rstd*g[t+256]+ b[t+256];
    __syncthreads();
  }
  if (blockIdx.x == 0) { wsf[W_XIN+t]=xin[t]; wsf[W_XIN+t+256]=xin[t+256]; }
  int lane = t & 63, w = t >> 6;
  float4 xa = *(const float4*)&xin[lane*4];
  float4 xb = *(const float4*)&xin[256+lane*4];
  const float* W = ipw + (size_t)l*1536*DD;
  int row0 = blockIdx.x*16;
  for (int p=0; p<4; ++p){
    int row = row0 + p*4 + w;
    const float* wr = W + (size_t)row*DD;
    float s = dot4(*(const float4*)&wr[lane*4], xa)
            + dot4(*(const float4*)&wr[256+lane*4], xb);
    for (int off=32; off; off>>=1) s += __shfl_xor(s, off);
    if (lane==0){
      float val = s + ipb[(size_t)l*1536 + row];
      wsf[W_QKV+row] = val;
      if (row >= 512 && row < 1024)
        out[O_KOUT + (size_t)l*TKV*DD + (size_t)SS*DD + (row-512)] = val;
      else if (row >= 1024)
        out[O_VOUT + (size_t)l*TKV*DD + (size_t)SS*DD + (row-1024)] = val;
    }
  }
}

// flash-decode partials per (head, chunk of 128 positions); also copies K/V to out
__global__ __launch_bounds__(128) void attn_kernel(int l,
    const float* __restrict__ kin, const float* __restrict__ vin,
    float* __restrict__ out, float* __restrict__ wsf)
{
  __shared__ float kl[128*33];
  __shared__ float vl[128*33];
  __shared__ float q_s[32];
  __shared__ float p_s[128];
  __shared__ float red[128];
  __shared__ float cacc[128];
  int t = threadIdx.x;
  int h = blockIdx.x >> 4, c = blockIdx.x & 15;
  int hd0 = h*32, s0 = c*128;
  if (t < 32) q_s[t] = wsf[W_QKV + hd0 + t];
  const float* kb = kin + (size_t)l*SS*DD;
  const float* vb = vin + (size_t)l*SS*DD;
  float* ko = out + O_KOUT + (size_t)l*TKV*DD;
  float* vo = out + O_VOUT + (size_t)l*TKV*DD;
  for (int idx = t; idx < 1024; idx += 128){
    int row = idx >> 3, c4 = idx & 7;
    int s = s0 + row;
    float4 kv, vv;
    if (s < SS){
      kv = *(const float4*)&kb[(size_t)s*DD + hd0 + c4*4];
      vv = *(const float4*)&vb[(size_t)s*DD + hd0 + c4*4];
    } else {
      kv = *(const float4*)&wsf[W_QKV + 512 + hd0 + c4*4];
      vv = *(const float4*)&wsf[W_QKV + 1024 + hd0 + c4*4];
    }
    int lb = row*33 + c4*4;
    kl[lb+0]=kv.x; kl[lb+1]=kv.y; kl[lb+2]=kv.z; kl[lb+3]=kv.w;
    vl[lb+0]=vv.x; vl[lb+1]=vv.y; vl[lb+2]=vv.z; vl[lb+3]=vv.w;
  }
  __syncthreads();
  // coalesced scalar stores (out base is not 16B-aligned: +1537 floats)
  for (int idx = t; idx < 4096; idx += 128){
    int row = idx >> 5, col = idx & 31;
    size_t go = (size_t)(s0+row)*DD + hd0 + col;
    ko[go] = kl[row*33+col];
    vo[go] = vl[row*33+col];
  }
  // scores: one row per thread
  float acc = 0.f;
  {
    int row = t;
    #pragma unroll
    for (int j=0;j<32;++j) acc += kl[row*33+j]*q_s[j];
  }
  float sc = acc * 0.17677669529663687f;  // 1/sqrt(32)
  red[t] = sc; __syncthreads();
  for (int off=64; off; off>>=1){ if (t<off) red[t]=fmaxf(red[t],red[t+off]); __syncthreads(); }
  float m = red[0]; __syncthreads();
  float p = expf(sc - m);
  p_s[t] = p;
  red[t] = p; __syncthreads();
  for (int off=64; off; off>>=1){ if (t<off) red[t]+=red[t+off]; __syncthreads(); }
  float lsum = red[0];
  // ctx partial: lanes<->d, 4 row-groups
  int g = t>>5, j = t&31;
  float ca = 0.f;
  #pragma unroll
  for (int i=0;i<32;++i){ int r = g*32+i; ca += p_s[r]*vl[r*33+j]; }
  cacc[t] = ca; __syncthreads();
  float* pbase = &wsf[W_PART + (size_t)(h*16+c)*34];
  if (t < 32) pbase[t] = cacc[t]+cacc[32+t]+cacc[64+t]+cacc[96+t];
  if (t == 0){ pbase[32]=m; pbase[33]=lsum; }
}

// combine flash partials (redundant per block), out-projection, residual
__global__ __launch_bounds__(256) void outproj_kernel(int l,
    const float* __restrict__ ow, const float* __restrict__ ob,
    const float* __restrict__ f2b, float* __restrict__ wsf)
{
  __shared__ __align__(16) float ctx[DD];
  int t = threadIdx.x;
  int h = t >> 4, sub = t & 15;
  const float* pbb = &wsf[W_PART + (size_t)(h*16+sub)*34];
  float m_c = pbb[32], l_c = pbb[33];
  float M = m_c;
  for (int off=8; off; off>>=1) M = fmaxf(M, __shfl_xor(M, off, 16));
  float e = expf(m_c - M);
  float Le = e*l_c;
  for (int off=8; off; off>>=1) Le += __shfl_xor(Le, off, 16);
  for (int j=0;j<32;++j){
    float cv = e*pbb[j];
    for (int off=8; off; off>>=1) cv += __shfl_xor(cv, off, 16);
    if (sub == 0) ctx[h*32+j] = cv / Le;
  }
  __syncthreads();
  int lane = t&63, w = t>>6;
  float4 xa = *(const float4*)&ctx[lane*4];
  float4 xb = *(const float4*)&ctx[256+lane*4];
  const float* W = ow + (size_t)l*DD*DD;
  int e0 = blockIdx.x*8;
  for (int p=0;p<2;++p){
    int row = e0 + p*4 + w;
    const float* wr = W + (size_t)row*DD;
    float s = dot4(*(const float4*)&wr[lane*4], xa)
            + dot4(*(const float4*)&wr[256+lane*4], xb);
    for (int off=32; off; off>>=1) s += __shfl_xor(s, off);
    if (lane==0) wsf[W_RES+row] = wsf[W_XIN+row] + s + ob[(size_t)l*DD+row];
  }
  if (blockIdx.x==0){
    wsf[W_FF+t]     = f2b[(size_t)l*DD+t];
    wsf[W_FF+t+256] = f2b[(size_t)l*DD+t+256];
  }
}

// LN1 (redundant) + FFN1 rows + FFN2 partial accumulation (fp32 atomics)
__global__ __launch_bounds__(256) void ffn_kernel(int l,
    const float* __restrict__ l1w, const float* __restrict__ l1b,
    const float* __restrict__ f1w, const float* __restrict__ f1b,
    const float* __restrict__ f2w, float* __restrict__ wsf)
{
  __shared__ __align__(16) float xln[DD];
  __shared__ float hdn[32];
  __shared__ float red[256];
  int t = threadIdx.x;
  float r0 = wsf[W_RES+t], r1 = wsf[W_RES+t+256];
  red[t]=r0+r1; __syncthreads();
  for (int off=128; off; off>>=1){ if (t<off) red[t]+=red[t+off]; __syncthreads(); }
  float mean = red[0]*(1.f/512.f); __syncthreads();
  float d0=r0-mean, d1=r1-mean;
  red[t]=d0*d0+d1*d1; __syncthreads();
  for (int off=128; off; off>>=1){ if (t<off) red[t]+=red[t+off]; __syncthreads(); }
  float rstd = rsqrtf(red[0]*(1.f/512.f)+1e-5f); __syncthreads();
  const float* g = l1w + (size_t)l*DD;
  const float* b = l1b + (size_t)l*DD;
  xln[t]     = d0*rstd*g[t]    + b[t];
  xln[t+256] = d1*rstd*g[t+256]+ b[t+256];
  __syncthreads();
  if (blockIdx.x==0){ wsf[W_XLN+t]=xln[t]; wsf[W_XLN+t+256]=xln[t+256]; }
  int lane=t&63, w=t>>6;
  float4 xa = *(const float4*)&xln[lane*4];
  float4 xb = *(const float4*)&xln[256+lane*4];
  int f0 = blockIdx.x*32;
  const float* W1 = f1w + (size_t)l*FFD*DD;
  for (int p=0;p<8;++p){
    int f = f0 + p*4 + w;
    const float* wr = W1 + (size_t)f*DD;
    float s = dot4(*(const float4*)&wr[lane*4], xa)
            + dot4(*(const float4*)&wr[256+lane*4], xb);
    for (int off=32; off; off>>=1) s += __shfl_xor(s, off);
    if (lane==0) hdn[f-f0] = fmaxf(s + f1b[(size_t)l*FFD+f], 0.f);
  }
  __syncthreads();
  int fi = lane&31, esub = lane>>5;
  float hv = hdn[fi];
  const float* W2 = f2w + (size_t)l*DD*FFD + f0;
  for (int p=0;p<64;++p){
    int e2 = p*8 + w*2 + esub;
    float val = W2[(size_t)e2*FFD + fi] * hv;
    for (int off=16; off; off>>=1) val += __shfl_xor(val, off, 32);
    if (fi==0) atomicAdd(&wsf[W_FF+e2], val);
  }
}

__global__ __launch_bounds__(256) void logits_kernel(
    const float* __restrict__ pw, const float* __restrict__ pbias,
    const float* __restrict__ l2w, const float* __restrict__ l2b,
    float* __restrict__ out, float* __restrict__ wsf)
{
  __shared__ __align__(16) float xin[DD];
  __shared__ float red[256];
  int t = threadIdx.x;
  float r0 = wsf[W_XLN+t] + wsf[W_FF+t];
  float r1 = wsf[W_XLN+t+256] + wsf[W_FF+t+256];
  red[t] = r0+r1; __syncthreads();
  for (int off=128; off; off>>=1){ if (t<off) red[t]+=red[t+off]; __syncthreads(); }
  float mean = red[0]*(1.f/512.f); __syncthreads();
  float d0=r0-mean, d1=r1-mean;
  red[t]=d0*d0+d1*d1; __syncthreads();
  for (int off=128; off; off>>=1){ if (t<off) red[t]+=red[t+off]; __syncthreads(); }
  float rstd = rsqrtf(red[0]*(1.f/512.f)+1e-5f); __syncthreads();
  const float* g = l2w + (size_t)23*DD;
  const float* b = l2b + (size_t)23*DD;
  xin[t]     = d0*rstd*g[t]    + b[t];
  xin[t+256] = d1*rstd*g[t+256]+ b[t+256];
  __syncthreads();
  int lane=t&63, w=t>>6;
  float4 xa = *(const float4*)&xin[lane*4];
  float4 xb = *(const float4*)&xin[256+lane*4];
  int row0 = blockIdx.x*16;
  for (int p=0;p<4;++p){
    int row = row0 + p*4 + w;
    if (row < VV){
      const float* wr = pw + (size_t)row*DD;
      float s = dot4(*(const float4*)&wr[lane*4], xa)
              + dot4(*(const float4*)&wr[256+lane*4], xb);
      for (int off=32; off; off>>=1) s += __shfl_xor(s, off);
      if (lane==0) out[O_LOGITS+row] = s + pbias[row];
    }
  }
}

__global__ __launch_bounds__(256) void sampler_kernel(
    const int* __restrict__ y, const float* __restrict__ noise,
    float* __restrict__ out)
{
  __shared__ float lg[VV];
  __shared__ float lgc[VV];
  __shared__ int   pen[VV];
  __shared__ float rv[256];
  __shared__ int   ri[256];
  __shared__ float sM, sPiv, sZ;
  int t = threadIdx.x;
  for (int i=t;i<VV;i+=256){ lg[i]=out[O_LOGITS+i]; pen[i]=0; }
  __syncthreads();
  for (int i=t;i<1536;i+=256) pen[y[i]] = 1;
  __syncthreads();
  for (int i=t;i<VV;i+=256){
    if (pen[i]){ float s = lg[i]; lg[i] = (s<0.f) ? s*1.35f : s/1.35f; }
  }
  __syncthreads();
  for (int i=t;i<VV;i+=256) lgc[i]=lg[i];
  __syncthreads();
  for (int it=0; it<15; ++it){
    float bv = -INFINITY; int bi = VV;
    for (int i=t;i<VV;i+=256){ float v2=lgc[i]; if (v2>bv){bv=v2;bi=i;} }
    rv[t]=bv; ri[t]=bi; __syncthreads();
    for (int off=128; off; off>>=1){
      if (t<off){
        float v2=rv[t+off]; int i2=ri[t+off];
        if (v2>rv[t] || (v2==rv[t] && i2<ri[t])){ rv[t]=v2; ri[t]=i2; }
      }
      __syncthreads();
    }
    if (t==0){
      if (it==0)  sM   = rv[0];
      if (it==14) sPiv = rv[0];
      lgc[ri[0]] = -INFINITY;
    }
    __syncthreads();
  }
  float zl = 0.f;
  for (int i=t;i<VV;i+=256){
    float lv = lg[i];
    float pv = (lv < sPiv) ? 0.f : expf(lv - sM);
    lgc[i] = pv; zl += pv;
  }
  rv[t]=zl; __syncthreads();
  for (int off=128; off; off>>=1){ if (t<off) rv[t]+=rv[t+off]; __syncthreads(); }
  if (t==0) sZ = rv[0];
  __syncthreads();
  float bv=-INFINITY; int bi=VV;
  for (int i=t;i<VV;i+=256){
    float val = (lgc[i]/sZ)/noise[i];
    if (val>bv){bv=val;bi=i;}
  }
  rv[t]=bv; ri[t]=bi; __syncthreads();
  for (int off=128; off; off>>=1){
    if (t<off){
      float v2=rv[t+off]; int i2=ri[t+off];
      if (v2>rv[t] || (v2==rv[t] && i2<ri[t])){ rv[t]=v2; ri[t]=i2; }
    }
    __syncthreads();
  }
  if (t==0){
    float sf = (float)ri[0];
    out[O_SAMP] = sf;
    out[O_YNEW+1536] = sf;
  }
}

extern "C" void kernel_launch(void* const* d_in, const int* in_sizes, int n_in,
                              void* d_out, int out_size, void* d_ws, size_t ws_size,
                              hipStream_t stream)
{
  const int*   y    = (const int*)d_in[0];
  const float* k    = (const float*)d_in[1];
  const float* v    = (const float*)d_in[2];
  const float* yemb = (const float*)d_in[3];
  const float* alpha= (const float*)d_in[5];
  const float* emb  = (const float*)d_in[6];
  const float* ipw  = (const float*)d_in[7];
  const float* ipb  = (const float*)d_in[8];
  const float* ow   = (const float*)d_in[9];
  const float* ob   = (const float*)d_in[10];
  const float* l1w  = (const float*)d_in[11];
  const float* l1b  = (const float*)d_in[12];
  const float* l2w  = (const float*)d_in[13];
  const float* l2b  = (const float*)d_in[14];
  const float* f1w  = (const float*)d_in[15];
  const float* f1b  = (const float*)d_in[16];
  const float* f2w  = (const float*)d_in[17];
  const float* f2b  = (const float*)d_in[18];
  const float* pw   = (const float*)d_in[19];
  const float* pb   = (const float*)d_in[20];
  const float* noise= (const float*)d_in[21];
  float* out = (float*)d_out;
  float* wsf = (float*)d_ws;

  setup_kernel<<<768,256,0,stream>>>(y, yemb, emb, alpha, out, wsf);
  for (int l=0; l<24; ++l){
    qkv_kernel<<<96,256,0,stream>>>(l, ipw, ipb, l2w, l2b, out, wsf);
    attn_kernel<<<256,128,0,stream>>>(l, k, v, out, wsf);
    outproj_kernel<<<64,256,0,stream>>>(l, ow, ob, f2b, wsf);
    ffn_kernel<<<64,256,0,stream>>>(l, l1w, l1b, f1w, f1b, f2w, wsf);
  }
  logits_kernel<<<65,256,0,stream>>>(pw, pb, l2w, l2b, out, wsf);
  sampler_kernel<<<1,256,0,stream>>>(y, noise, out);
}